// Round 14
// baseline (285.395 us; speedup 1.0000x reference)
//
#include <hip/hip_runtime.h>

typedef __bf16 bf16x8 __attribute__((ext_vector_type(8)));
typedef float f32x4 __attribute__((ext_vector_type(4)));
typedef unsigned short u16;

__device__ __forceinline__ u16 f2bf(float f) {
  unsigned int u = __builtin_bit_cast(unsigned int, f);
  u += 0x7fff + ((u >> 16) & 1);   // RNE
  return (u16)(u >> 16);
}
__device__ __forceinline__ float bf2f(u16 s) {
  unsigned int u = ((unsigned int)s) << 16;
  return __builtin_bit_cast(float, u);
}
__device__ __forceinline__ void unp8(uint4 u, float* f) {
  f[0] = bf2f(u.x & 0xffff); f[1] = bf2f(u.x >> 16);
  f[2] = bf2f(u.y & 0xffff); f[3] = bf2f(u.y >> 16);
  f[4] = bf2f(u.z & 0xffff); f[5] = bf2f(u.z >> 16);
  f[6] = bf2f(u.w & 0xffff); f[7] = bf2f(u.w >> 16);
}
__device__ __forceinline__ uint4 pk8(const float* f) {
  uint4 u;
  u.x = (unsigned)f2bf(f[0]) | ((unsigned)f2bf(f[1]) << 16);
  u.y = (unsigned)f2bf(f[2]) | ((unsigned)f2bf(f[3]) << 16);
  u.z = (unsigned)f2bf(f[4]) | ((unsigned)f2bf(f[5]) << 16);
  u.w = (unsigned)f2bf(f[6]) | ((unsigned)f2bf(f[7]) << 16);
  return u;
}

// async global->LDS, 16B per lane. LDS dest = wave-uniform base + lane*16 (HW).
__device__ __forceinline__ void gl_lds16(const u16* g, u16* l) {
  __builtin_amdgcn_global_load_lds(
      (const __attribute__((address_space(1))) void*)g,
      (__attribute__((address_space(3))) void*)l, 16, 0, 0);
}

// ---------------------------------------------------------------------------
// gemm_lt: 128x256 tile, 2-phase, single-buffered 48KB LDS, ~110 regs -> 2
// blocks/CU. Short-K GEMMs with LARGE grids (>=512 blocks).
// MODE 0: bf16 out, bias = col-select (bias_col col<512, bias_col2 col>=512)
// MODE 1: bf16 out, C = exp2(alpha*acc)
// ---------------------------------------------------------------------------
template <int MODE>
__global__ __launch_bounds__(512, 4) void gemm_lt(
    const u16* __restrict__ A, int lda, unsigned long long sA,
    const u16* __restrict__ Bt, int ldb, unsigned long long sB,
    u16* __restrict__ Cout, int ldc, unsigned long long sC,
    int K, float alpha, int tn,
    const float* __restrict__ bias_col, const float* __restrict__ bias_col2) {
  __shared__ u16 lds[24576];   // As[128][64] @0, Bs[256][64] @8192 (48KB)
  u16* As = lds;
  u16* Bs = lds + 8192;

  const int t = threadIdx.x;
  const int lane = t & 63;
  const int w = t >> 6;
  const int bz = blockIdx.z;
  A  += (size_t)bz * sA;
  Bt += (size_t)bz * sB;

  // XCD swizzle (nwg % 8 == 0 guaranteed by launch)
  const int nwg = gridDim.x;
  const int flat = blockIdx.x;
  const int wg = (flat & 7) * (nwg >> 3) + (flat >> 3);
  const int m0 = (wg / tn) * 128;
  const int n0 = (wg % tn) * 256;

  const int NKT = K >> 6;

  // staging source per lane: row = +sr, col16 = (lane&7) ^ sr  (pre-swizzle)
  const int sr = lane >> 3;
  const int sc = ((lane & 7) ^ sr) * 8;
  const u16* gA = A  + (size_t)(m0 + w * 16 + sr) * lda + sc;   // 2 loads/wave
  const u16* gB = Bt + (size_t)(n0 + w * 32 + sr) * ldb + sc;   // 4 loads/wave
  const size_t a8 = (size_t)8 * lda, b8 = (size_t)8 * ldb;
  u16* lA = As + w * 1024;
  u16* lB = Bs + w * 2048;

  const int wr = w >> 2, wc = w & 3;     // 2 (M) x 4 (N) waves
  const int fr = lane & 15, kg = lane >> 4;
  const int frx = (fr & 7) << 4;

  f32x4 acc[4][4] = {};                  // 64 regs
  bf16x8 af[4][2];                       // 32 regs
  bf16x8 bqn[2];                         // 8 regs

  for (int kt = 0; kt < NKT; ++kt) {
    if (kt) __builtin_amdgcn_s_barrier();         // prev tile fully consumed
    {
      const size_t ko = (size_t)kt * 64;
      gl_lds16(gA + ko, lA);
      gl_lds16(gA + a8 + ko, lA + 512);
#pragma unroll
      for (int j = 0; j < 4; ++j)
        gl_lds16(gB + (size_t)j * b8 + ko, lB + j * 512);
    }
    asm volatile("s_waitcnt vmcnt(0)" ::: "memory");
    __builtin_amdgcn_s_barrier();                 // tile resident

#pragma unroll
    for (int m = 0; m < 4; ++m) {
      const int R = wr * 64 + m * 16 + fr;
#pragma unroll
      for (int kk = 0; kk < 2; ++kk)
        af[m][kk] = *reinterpret_cast<const bf16x8*>(
            As + R * 64 + (((kk * 64 + kg * 16) ^ frx) >> 1));
    }
#pragma unroll
    for (int n = 0; n < 4; ++n) {
      const int R = wc * 64 + n * 16 + fr;
#pragma unroll
      for (int kk = 0; kk < 2; ++kk)
        bqn[kk] = *reinterpret_cast<const bf16x8*>(
            Bs + R * 64 + (((kk * 64 + kg * 16) ^ frx) >> 1));
#pragma unroll
      for (int kk = 0; kk < 2; ++kk)
#pragma unroll
        for (int m = 0; m < 4; ++m)
          acc[m][n] = __builtin_amdgcn_mfma_f32_16x16x32_bf16(
              af[m][kk], bqn[kk], acc[m][n], 0, 0, 0);
    }
  }

  // epilogue: two 64x256 halves (32KB) through LDS, coalesced stores
  u16* cs = lds;
  const size_t cbs = (size_t)bz * sC;
#pragma unroll
  for (int h = 0; h < 2; ++h) {
    __syncthreads();
    if (wr == h) {
#pragma unroll
      for (int m = 0; m < 4; ++m) {
        const int rl = m * 16 + (kg << 2);
#pragma unroll
        for (int n = 0; n < 4; ++n) {
          const int col = wc * 64 + n * 16 + fr;
          float bcc = 0.0f;
          if (MODE == 0 && bias_col) {
            const int gc = n0 + col;
            bcc = (bias_col2 && gc >= 512) ? bias_col2[gc - 512] : bias_col[gc & 511];
          }
#pragma unroll
          for (int r = 0; r < 4; ++r) {
            float v = acc[m][n][r] * alpha;
            if (MODE == 1) v = exp2f(v);
            else v += bcc;
            cs[(rl + r) * 256 + col] = f2bf(v);
          }
        }
      }
    }
    __syncthreads();
#pragma unroll
    for (int it = 0; it < 4; ++it) {
      const int off = (it * 512 + t) * 8;
      const int row = off >> 8, col = off & 255;
      *reinterpret_cast<uint4*>(
          &Cout[cbs + (size_t)(m0 + h * 64 + row) * ldc + (n0 + col)]) =
          *reinterpret_cast<const uint4*>(&cs[off]);
    }
  }
}

// ---------------------------------------------------------------------------
// 256x256 8-phase GEMM (PV): MODE 2 = C=acc + row-sums of A via ones-MFMA.
// blockIdx.y = K-split index: K elems [y*K,(y+1)*K), out += y*sSplit.
// ---------------------------------------------------------------------------
template <int MODE>
__global__ __launch_bounds__(512, 2) void gemm_nt256(
    const u16* __restrict__ A, int lda, unsigned long long sA,
    const u16* __restrict__ Bt, int ldb, unsigned long long sB,
    u16* __restrict__ Cout, int ldc, unsigned long long sC,
    unsigned long long sSplit, int K, float alpha, int tn,
    float* __restrict__ psum) {
  __shared__ u16 lds[2][4][8192];

  const int t = threadIdx.x;
  const int lane = t & 63;
  const int w = t >> 6;
  const int bz = blockIdx.z;
  A  += (size_t)bz * sA + (size_t)blockIdx.y * K;
  Bt += (size_t)bz * sB + (size_t)blockIdx.y * K;
  Cout += (size_t)blockIdx.y * sSplit;

  const int nwg = gridDim.x;
  const int flat = blockIdx.x;
  const int wg = (flat & 7) * (nwg >> 3) + (flat >> 3);
  const int tt = tn << 1;
  const int p  = wg / tt;
  const int rr = wg - p * tt;
  const int m0 = (p * 2 + (rr & 1)) * 256;
  const int n0 = (rr >> 1) * 256;

  const int NKT = K >> 6;

  const int sr = lane >> 3;
  const int sc = ((lane & 7) ^ sr) * 8;
  const u16* gA = A  + (size_t)(m0 + w * 16 + sr) * lda + sc;
  const u16* gB = Bt + (size_t)(n0 + w * 16 + sr) * ldb + sc;
  const size_t a128 = (size_t)128 * lda, b128 = (size_t)128 * ldb;
  const size_t a8 = (size_t)8 * lda, b8 = (size_t)8 * ldb;
  const int lws = w * 1024;

  auto stage = [&](int slot, int region, int kt) {
    kt = kt < NKT ? kt : NKT - 1;
    u16* l = &lds[slot][region][lws];
    if (region < 2) {
      const u16* g = gA + (region ? a128 : 0) + (size_t)kt * 64;
      gl_lds16(g, l);
      gl_lds16(g + a8, l + 512);
    } else {
      const u16* g = gB + (region == 3 ? b128 : 0) + (size_t)kt * 64;
      gl_lds16(g, l);
      gl_lds16(g + b8, l + 512);
    }
  };

  const int wr = w >> 2, wc = w & 3;
  const int fr = lane & 15, kg = lane >> 4;
  const int frx = (fr & 7) << 4;

  f32x4 acc[8][4] = {};
  f32x4 sacc[8] = {};
  bf16x8 af[4][2], bq[2][2];
  union { u16 u[8]; bf16x8 v; } ou;
#pragma unroll
  for (int i = 0; i < 8; ++i) ou.u[i] = 0x3F80;   // bf16 1.0
  const bf16x8 onesb = ou.v;

#define LDA_(s, qm)                                                            \
  {                                                                            \
    const u16* Ab = &lds[s][0][0];                                             \
    _Pragma("unroll") for (int m = 0; m < 4; ++m) {                            \
      const int R = wr * 128 + (qm) * 64 + m * 16 + fr;                        \
      _Pragma("unroll") for (int kk = 0; kk < 2; ++kk)                         \
          af[m][kk] = *reinterpret_cast<const bf16x8*>(                        \
              Ab + R * 64 + (((kk * 64 + kg * 16) ^ frx) >> 1));               \
    }                                                                          \
  }
#define LDB_(s, qn)                                                            \
  {                                                                            \
    const u16* Bb = &lds[s][2][0];                                             \
    _Pragma("unroll") for (int n = 0; n < 2; ++n) {                            \
      const int R = wc * 64 + (qn) * 32 + n * 16 + fr;                         \
      _Pragma("unroll") for (int kk = 0; kk < 2; ++kk)                         \
          bq[n][kk] = *reinterpret_cast<const bf16x8*>(                        \
              Bb + R * 64 + (((kk * 64 + kg * 16) ^ frx) >> 1));               \
    }                                                                          \
  }
#define PH(s, qm, qn, DOA, DOB, ss, rr_, kt, VM)                               \
  {                                                                            \
    if (DOA) LDA_(s, qm)                                                       \
    if (DOB) LDB_(s, qn)                                                       \
    stage(ss, rr_, kt);                                                        \
    __builtin_amdgcn_s_barrier();                                              \
    asm volatile("s_waitcnt lgkmcnt(0)" ::: "memory");                         \
    __builtin_amdgcn_s_setprio(1);                                             \
    _Pragma("unroll") for (int kk = 0; kk < 2; ++kk)                           \
    _Pragma("unroll") for (int m = 0; m < 4; ++m)                              \
    _Pragma("unroll") for (int n = 0; n < 2; ++n)                              \
        acc[(qm)*4 + m][(qn)*2 + n] = __builtin_amdgcn_mfma_f32_16x16x32_bf16( \
            af[m][kk], bq[n][kk], acc[(qm)*4 + m][(qn)*2 + n], 0, 0, 0);       \
    if (MODE == 2 && (DOA) && wc == 0) {                                       \
      _Pragma("unroll") for (int kk = 0; kk < 2; ++kk)                         \
      _Pragma("unroll") for (int m = 0; m < 4; ++m)                            \
          sacc[(qm)*4 + m] = __builtin_amdgcn_mfma_f32_16x16x32_bf16(          \
              af[m][kk], onesb, sacc[(qm)*4 + m], 0, 0, 0);                    \
    }                                                                          \
    __builtin_amdgcn_s_setprio(0);                                             \
    if (VM) asm volatile("s_waitcnt vmcnt(2)" ::: "memory");                   \
    __builtin_amdgcn_s_barrier();                                              \
  }

  stage(0, 0, 0); stage(0, 1, 0); stage(0, 2, 0); stage(0, 3, 0);
  stage(1, 0, 1);
  asm volatile("s_waitcnt vmcnt(2)" ::: "memory");
  __builtin_amdgcn_s_barrier();

  for (int j = 0; j < (NKT >> 1); ++j) {
    const int k1 = 2 * j + 1, k2 = 2 * j + 2, k3 = 2 * j + 3;
    PH(0, 0, 0, 1, 1, 1, 1, k1, 0)
    PH(0, 0, 1, 0, 1, 1, 2, k1, 0)
    PH(0, 1, 1, 1, 0, 1, 3, k1, 0)
    PH(0, 1, 0, 0, 1, 0, 0, k2, 1)
    PH(1, 0, 0, 1, 1, 0, 1, k2, 0)
    PH(1, 0, 1, 0, 1, 0, 2, k2, 0)
    PH(1, 1, 1, 1, 0, 0, 3, k2, 0)
    PH(1, 1, 0, 0, 1, 1, 0, k3, 1)
  }
#undef PH
#undef LDB_
#undef LDA_

  __syncthreads();
  u16* cs = &lds[0][0][0];
#pragma unroll
  for (int a = 0; a < 8; ++a) {
    const int row = wr * 128 + a * 16 + (kg << 2);
#pragma unroll
    for (int b = 0; b < 4; ++b) {
      const int col = wc * 64 + b * 16 + fr;
#pragma unroll
      for (int r = 0; r < 4; ++r)
        cs[(row + r) * 256 + col] = f2bf(acc[a][b][r] * alpha);
    }
  }
  __syncthreads();
  const size_t cbs = (size_t)bz * sC;
#pragma unroll
  for (int it = 0; it < 16; ++it) {
    const int off = (it * 512 + t) * 8;
    const int row = off >> 8, col = off & 255;
    *reinterpret_cast<uint4*>(&Cout[cbs + (size_t)(m0 + row) * ldc + (n0 + col)]) =
        *reinterpret_cast<const uint4*>(&cs[off]);
  }
  if (MODE == 2 && psum && wc == 0 && fr == 0) {
    const int Mrows = (nwg / tn) << 8;
    float* pp = psum + ((size_t)bz * gridDim.y + blockIdx.y) * Mrows + m0;
#pragma unroll
    for (int q = 0; q < 2; ++q)
#pragma unroll
      for (int m = 0; m < 4; ++m)
#pragma unroll
        for (int r = 0; r < 4; ++r)
          pp[wr * 128 + q * 64 + m * 16 + (kg << 2) + r] = sacc[q * 4 + m][r];
  }
}

// ---------------------------------------------------------------------------
// 128x128 m97-structure GEMM (v projection, final proj w/ fp32+residual)
// ---------------------------------------------------------------------------
template <bool OUT_F32>
__global__ __launch_bounds__(256) void gemm_nt(
    const u16* __restrict__ A, int lda, unsigned long long sA,
    const u16* __restrict__ Bt, int ldb, unsigned long long sB,
    void* __restrict__ Cout, int ldc, unsigned long long sC,
    int K, float alpha,
    const float* __restrict__ bias_row, const float* __restrict__ bias_col,
    const float* __restrict__ residual, unsigned long long sRes) {
  __shared__ u16 lds[128 * 128];
  u16* As = lds;
  u16* Bs = lds + 8192;

  const int t = threadIdx.x;
  const int bz = blockIdx.z;
  A  += (size_t)bz * sA;
  Bt += (size_t)bz * sB;
  const int m0 = blockIdx.x * 128;
  const int n0 = blockIdx.y * 128;

  const int lane = t & 63;
  const int w = t >> 6;

  const int srow = w * 32 + (lane >> 3);
  const int scol = (lane & 7) * 8;
  const u16* gA = A  + (size_t)(m0 + srow) * lda + scol;
  const u16* gB = Bt + (size_t)(n0 + srow) * ldb + scol;
  u16* lA = As + w * 2048;
  u16* lB = Bs + w * 2048;

  f32x4 acc[4][4] = {};
  const int wm = (w >> 1) * 64;
  const int wn = (w & 1) * 64;
  const int fr = lane & 15;
  const int kg = lane >> 4;

  for (int k0 = 0; k0 < K; k0 += 64) {
    __syncthreads();
#pragma unroll
    for (int i = 0; i < 4; ++i) {
      gl_lds16(gA + (size_t)(i * 8) * lda + k0, lA + i * 512);
      gl_lds16(gB + (size_t)(i * 8) * ldb + k0, lB + i * 512);
    }
    __syncthreads();

#pragma unroll
    for (int kk = 0; kk < 2; ++kk) {
      bf16x8 af[4], bfr[4];
#pragma unroll
      for (int m = 0; m < 4; ++m)
        af[m] = *reinterpret_cast<const bf16x8*>(
            &As[(wm + m * 16 + fr) * 64 + kk * 32 + kg * 8]);
#pragma unroll
      for (int n = 0; n < 4; ++n)
        bfr[n] = *reinterpret_cast<const bf16x8*>(
            &Bs[(wn + n * 16 + fr) * 64 + kk * 32 + kg * 8]);
#pragma unroll
      for (int m = 0; m < 4; ++m)
#pragma unroll
        for (int n = 0; n < 4; ++n)
          acc[m][n] = __builtin_amdgcn_mfma_f32_16x16x32_bf16(af[m], bfr[n], acc[m][n], 0, 0, 0);
    }
  }

  const size_t cbase = (size_t)bz * sC;
  const size_t rbase = (size_t)bz * sRes;
  const int rq = kg * 4;

  if (OUT_F32) {
    float* Cf = reinterpret_cast<float*>(Cout);
    float* lf = reinterpret_cast<float*>(lds);
#pragma unroll
    for (int h = 0; h < 2; ++h) {
      __syncthreads();
      if ((wm >> 6) == h) {
#pragma unroll
        for (int m = 0; m < 4; ++m)
#pragma unroll
          for (int n = 0; n < 4; ++n) {
            const float bc = bias_col ? bias_col[n0 + wn + n * 16 + fr] : 0.0f;
#pragma unroll
            for (int r = 0; r < 4; ++r)
              lf[(m * 16 + rq + r) * 128 + (wn + n * 16 + fr)] =
                  acc[m][n][r] * alpha + bc;
          }
      }
      __syncthreads();
#pragma unroll
      for (int it = 0; it < 8; ++it) {
        const int off = (it * 256 + t) * 4;
        const int row = off >> 7, col = off & 127;
        const int grow = m0 + h * 64 + row, gcol = n0 + col;
        float4 v = *reinterpret_cast<const float4*>(&lf[off]);
        if (bias_row) {
          const float br = bias_row[grow];
          v.x += br; v.y += br; v.z += br; v.w += br;
        }
        if (residual) {
          const float4 rx = *reinterpret_cast<const float4*>(
              &residual[rbase + (size_t)grow * ldc + gcol]);
          v.x += rx.x; v.y += rx.y; v.z += rx.z; v.w += rx.w;
        }
        *reinterpret_cast<float4*>(&Cf[cbase + (size_t)grow * ldc + gcol]) = v;
      }
    }
  } else {
    __syncthreads();
#pragma unroll
    for (int m = 0; m < 4; ++m) {
#pragma unroll
      for (int n = 0; n < 4; ++n) {
        const int gcol = n0 + wn + n * 16 + fr;
        const float bc = bias_col ? bias_col[gcol] : 0.0f;
#pragma unroll
        for (int r = 0; r < 4; ++r) {
          const int grow = m0 + wm + m * 16 + rq + r;
          float v = acc[m][n][r] * alpha + bc;
          if (bias_row) v += bias_row[grow];
          lds[(wm + m * 16 + rq + r) * 128 + (wn + n * 16 + fr)] = f2bf(v);
        }
      }
    }
    __syncthreads();
    u16* Cb = reinterpret_cast<u16*>(Cout);
#pragma unroll
    for (int j = 0; j < 8; ++j) {
      const int off = (j * 256 + t) * 8;
      const int row = off >> 7, col = off & 127;
      *reinterpret_cast<uint4*>(&Cb[cbase + (size_t)(m0 + row) * ldc + (n0 + col)]) =
          *reinterpret_cast<const uint4*>(&lds[off]);
    }
  }
}

// ---------------------------------------------------------------------------
// GroupNorm, split for full-GPU occupancy: gn_part (partial sums per N/4
// chunk, 512 blocks) + gn_apply (normalize+write, 512 blocks).
// x fp32 [B,C,N] -> h_t bf16 [B,N,C]; group = 16 channels.
// ---------------------------------------------------------------------------
__global__ __launch_bounds__(256) void gn_part(
    const float* __restrict__ x, float2* __restrict__ part, int C, int N) {
  const int g = blockIdx.x, b = blockIdx.y, ch = blockIdx.z;
  const int t = threadIdx.x;
  const float* xb = x + ((size_t)b * C + g * 16) * N + ch * (N >> 2);

  float s = 0.f, q = 0.f;
#pragma unroll
  for (int c = 0; c < 16; ++c) {
    const float4 v = reinterpret_cast<const float4*>(xb + (size_t)c * N)[t];
    s += v.x + v.y + v.z + v.w;
    q += v.x * v.x + v.y * v.y + v.z * v.z + v.w * v.w;
  }
#pragma unroll
  for (int o = 32; o > 0; o >>= 1) { s += __shfl_down(s, o); q += __shfl_down(q, o); }
  __shared__ float rs[4], rq[4];
  const int lane = t & 63, wid = t >> 6;
  if (lane == 0) { rs[wid] = s; rq[wid] = q; }
  __syncthreads();
  if (t == 0) {
    part[(((size_t)b * 32 + g) << 2) + ch] =
        make_float2(rs[0] + rs[1] + rs[2] + rs[3], rq[0] + rq[1] + rq[2] + rq[3]);
  }
}

__global__ __launch_bounds__(256) void gn_apply(
    const float* __restrict__ x, const float* __restrict__ gamma,
    const float* __restrict__ beta, const float2* __restrict__ part,
    u16* __restrict__ h_t, int C, int N) {
  const int g = blockIdx.x, b = blockIdx.y, ch = blockIdx.z;
  const int t = threadIdx.x;
  const float2* pp = &part[(((size_t)b * 32 + g) << 2)];
  const float2 p0 = pp[0], p1 = pp[1], p2 = pp[2], p3 = pp[3];
  const float S = p0.x + p1.x + p2.x + p3.x;
  const float Q = p0.y + p1.y + p2.y + p3.y;
  const float inv = 1.0f / (16.0f * (float)N);
  const float mean = S * inv;
  const float rstd = rsqrtf(Q * inv - mean * mean + 1e-6f);

  float gm[16], bt[16];
#pragma unroll
  for (int c = 0; c < 16; ++c) {
    gm[c] = gamma[g * 16 + c] * rstd;
    bt[c] = beta[g * 16 + c] - mean * gm[c];
  }
  const float* xb = x + ((size_t)b * C + g * 16) * N;
  u16* ho = h_t + (size_t)b * N * C + g * 16;
  const int n0 = ch * (N >> 2);
  for (int n = n0 + t; n < n0 + (N >> 2); n += 256) {
    union { u16 us[16]; uint4 v4[2]; } pk;
#pragma unroll
    for (int c = 0; c < 16; ++c) {
      float v = xb[(size_t)c * N + n];
      pk.us[c] = f2bf(v * gm[c] + bt[c]);
    }
    uint4* dst = reinterpret_cast<uint4*>(ho + (size_t)n * C);
    dst[0] = pk.v4[0];
    dst[1] = pk.v4[1];
  }
}

// convert 4 fp32 weight matrices (each n elems) to bf16, contiguous dst
__global__ __launch_bounds__(256) void wcvt4(
    const float* __restrict__ s0, const float* __restrict__ s1,
    const float* __restrict__ s2, const float* __restrict__ s3,
    u16* __restrict__ dst, int n) {
  const int i = (blockIdx.x * 256 + threadIdx.x) * 8;
  if (i >= n) return;
  const float* src = (blockIdx.y == 0) ? s0 : (blockIdx.y == 1) ? s1
                     : (blockIdx.y == 2) ? s2 : s3;
  const float4* s4 = reinterpret_cast<const float4*>(src + i);
  float4 a = s4[0], b = s4[1];
  float f[8] = {a.x, a.y, a.z, a.w, b.x, b.y, b.z, b.w};
  *reinterpret_cast<uint4*>(dst + (size_t)blockIdx.y * n + i) = pk8(f);
}

// o[i] = bf16( (p[i] + p[n+i]) / (psum[b][0][nn] + psum[b][1][nn]) )
__global__ __launch_bounds__(256) void reduce_pv(const u16* __restrict__ p,
                                                 const float* __restrict__ psum,
                                                 u16* __restrict__ o, int n) {
  const int i = (blockIdx.x * 256 + threadIdx.x) * 8;
  if (i >= n) return;
  const int row = i >> 9;             // b*4096 + nn
  const int b = row >> 12, nn = row & 4095;
  const float il = 1.0f / (psum[(size_t)(b * 2) * 4096 + nn] +
                           psum[(size_t)(b * 2 + 1) * 4096 + nn]);
  uint4 a = *reinterpret_cast<const uint4*>(p + i);
  uint4 bb = *reinterpret_cast<const uint4*>(p + n + i);
  float fa[8], fb[8];
  unp8(a, fa); unp8(bb, fb);
#pragma unroll
  for (int j = 0; j < 8; ++j) fa[j] = (fa[j] + fb[j]) * il;
  *reinterpret_cast<uint4*>(o + i) = pk8(fa);
}

// in-place o[i] /= psum[row]   (fallback path, unsplit PV, psum [b*N+n])
__global__ __launch_bounds__(256) void scale_o(u16* __restrict__ o,
                                               const float* __restrict__ psum,
                                               int n) {
  const int i = (blockIdx.x * 256 + threadIdx.x) * 8;
  if (i >= n) return;
  const float il = 1.0f / psum[i >> 9];
  uint4 a = *reinterpret_cast<const uint4*>(o + i);
  float fa[8];
  unp8(a, fa);
#pragma unroll
  for (int j = 0; j < 8; ++j) fa[j] *= il;
  *reinterpret_cast<uint4*>(o + i) = pk8(fa);
}

extern "C" void kernel_launch(void* const* d_in, const int* in_sizes, int n_in,
                              void* d_out, int out_size, void* d_ws, size_t ws_size,
                              hipStream_t stream) {
  const float* x     = (const float*)d_in[0];
  const float* gamma = (const float*)d_in[1];
  const float* beta  = (const float*)d_in[2];
  const float* wq    = (const float*)d_in[3];
  const float* bq    = (const float*)d_in[4];
  const float* wk    = (const float*)d_in[5];
  const float* bk    = (const float*)d_in[6];
  const float* wv    = (const float*)d_in[7];
  const float* bv    = (const float*)d_in[8];
  const float* wo    = (const float*)d_in[9];
  const float* bo    = (const float*)d_in[10];

  const int B = 4, C = 512, N = 4096;
  const size_t NC = (size_t)N * C;
  const size_t NN = (size_t)N * N;
  const size_t CC = (size_t)C * C;

  char* ws = (char*)d_ws;
  size_t off = 0;
  auto alloc = [&](size_t bytes) {
    size_t r = off;
    off = (off + bytes + 255) & ~(size_t)255;
    return r;
  };
  u16* wq_b = (u16*)(ws + alloc(CC * 2));   // wq,wk,wv,wo contiguous bf16
  u16* wk_b = (u16*)(ws + alloc(CC * 2));
  u16* wv_b = (u16*)(ws + alloc(CC * 2));
  u16* wo_b = (u16*)(ws + alloc(CC * 2));
  u16* h_t  = (u16*)(ws + alloc(B * NC * 2));
  u16* qk_t = (u16*)(ws + alloc(B * N * 1024 * 2));  // q|k; reused as PV partials
  u16* v_cn = (u16*)(ws + alloc(B * NC * 2));
  u16* o_t  = (u16*)(ws + alloc(B * NC * 2));
  float* psum = (float*)(ws + alloc((size_t)B * 2 * N * 4));  // row-sum partials
  float2* gnp = (float2*)(ws + alloc((size_t)B * 32 * 4 * 8));
  const size_t base_need = off;

  int s_batched = 0;
  u16* S;
  if (ws_size >= base_need + B * NN * 2) {
    S = (u16*)(ws + alloc(B * NN * 2));
    s_batched = 1;
  } else {
    S = (u16*)(ws + alloc(NN * 2));   // per-batch scores (assumed to fit)
  }
  u16* o_part = qk_t;   // 2 x B*NC bf16 == B*N*1024 bf16; qk_t dead after QK

  (void)wk_b;

  // weights fp32 -> bf16 (one launch, 4 matrices)
  wcvt4<<<dim3(CC / 2048, 4), 256, 0, stream>>>(wq, wk, wv, wo, wq_b, (int)CC);

  // groupnorm, split for full-GPU occupancy -> h_t [b,n,c]
  gn_part<<<dim3(32, B, 4), 256, 0, stream>>>(x, gnp, C, N);
  gn_apply<<<dim3(32, B, 4), 256, 0, stream>>>(x, gamma, beta, gnp, h_t, C, N);

  // fused q|k : qk_t[b,n,0:512]=q, [512:1024]=k  (128x256 lt kernel, 2/CU)
  gemm_lt<0><<<dim3((N / 128) * (1024 / 256), 1, B), 512, 0, stream>>>(
      h_t, C, NC, wq_b, C, 0, qk_t, 1024, (unsigned long long)N * 1024,
      C, 1.0f, 1024 / 256, bq, bk);
  // v : [b,co,n] = w[co,ci] * h_t[b,n,ci]^T + bv[co]  (512-block 128^2 kernel)
  dim3 gv(C / 128, N / 128, B);
  gemm_nt<false><<<gv, 256, 0, stream>>>(wv_b, C, 0, h_t, C, NC, v_cn, N, NC,
                                         C, 1.0f, bv, nullptr, nullptr, 0);

  // alpha folds 512^-0.5 and log2(e): S' = 2^(qk * alpha) = e^(qk * 512^-0.5)
  const float c1 = 0.06376694387439652f;
  if (s_batched) {
    // QK -> unnormalized P (bf16), 128x256 lt kernel (2 blocks/CU)
    gemm_lt<1><<<dim3((N / 128) * (N / 256), 1, B), 512, 0, stream>>>(
        qk_t, 1024, (unsigned long long)N * 1024, qk_t + 512, 1024,
        (unsigned long long)N * 1024, S, N, NN, C, c1, N / 256,
        nullptr, nullptr);
    // PV split-K=2: partials (alias qk_t) + exact row-sums via ones-MFMA
    gemm_nt256<2><<<dim3((N / 256) * (C / 256), 2, B), 512, 0, stream>>>(
        S, N, NN, v_cn, N, NC, o_part, C, NC, (unsigned long long)B * NC,
        N / 2, 1.0f, C / 256, psum);
    reduce_pv<<<dim3((int)(B * NC / 2048)), 256, 0, stream>>>(
        o_part, psum, o_t, (int)(B * NC));
  } else {
    for (int b = 0; b < B; ++b) {
      gemm_lt<1><<<dim3((N / 128) * (N / 256), 1, 1), 512, 0, stream>>>(
          qk_t + (size_t)b * N * 1024, 1024, 0, qk_t + (size_t)b * N * 1024 + 512,
          1024, 0, S, N, 0, C, c1, N / 256, nullptr, nullptr);
      gemm_nt256<2><<<dim3((N / 256) * (C / 256), 1, 1), 512, 0, stream>>>(
          S, N, 0, v_cn + (size_t)b * NC, N, 0, o_t + (size_t)b * NC, C, 0, 0,
          N, 1.0f, C / 256, psum + (size_t)b * N);
    }
    scale_o<<<dim3((int)(B * NC / 2048)), 256, 0, stream>>>(o_t, psum, (int)(B * NC));
  }

  // out[b,co,n] = wo[co,ci] * o_t[b,n,ci]^T + bo[co] + x[b,co,n]   (fp32)
  dim3 gf(C / 128, N / 128, B);
  gemm_nt<true><<<gf, 256, 0, stream>>>(wo_b, C, 0, o_t, C, NC, d_out, N, NC,
                                        C, 1.0f, bo, nullptr, x, NC);
}

// Round 15
// 278.934 us; speedup vs baseline: 1.0232x; 1.0232x over previous
//
#include <hip/hip_runtime.h>

typedef __bf16 bf16x8 __attribute__((ext_vector_type(8)));
typedef float f32x4 __attribute__((ext_vector_type(4)));
typedef unsigned short u16;

__device__ __forceinline__ u16 f2bf(float f) {
  unsigned int u = __builtin_bit_cast(unsigned int, f);
  u += 0x7fff + ((u >> 16) & 1);   // RNE
  return (u16)(u >> 16);
}
__device__ __forceinline__ float bf2f(u16 s) {
  unsigned int u = ((unsigned int)s) << 16;
  return __builtin_bit_cast(float, u);
}
__device__ __forceinline__ void unp8(uint4 u, float* f) {
  f[0] = bf2f(u.x & 0xffff); f[1] = bf2f(u.x >> 16);
  f[2] = bf2f(u.y & 0xffff); f[3] = bf2f(u.y >> 16);
  f[4] = bf2f(u.z & 0xffff); f[5] = bf2f(u.z >> 16);
  f[6] = bf2f(u.w & 0xffff); f[7] = bf2f(u.w >> 16);
}
__device__ __forceinline__ uint4 pk8(const float* f) {
  uint4 u;
  u.x = (unsigned)f2bf(f[0]) | ((unsigned)f2bf(f[1]) << 16);
  u.y = (unsigned)f2bf(f[2]) | ((unsigned)f2bf(f[3]) << 16);
  u.z = (unsigned)f2bf(f[4]) | ((unsigned)f2bf(f[5]) << 16);
  u.w = (unsigned)f2bf(f[6]) | ((unsigned)f2bf(f[7]) << 16);
  return u;
}

// async global->LDS, 16B per lane. LDS dest = wave-uniform base + lane*16 (HW).
__device__ __forceinline__ void gl_lds16(const u16* g, u16* l) {
  __builtin_amdgcn_global_load_lds(
      (const __attribute__((address_space(1))) void*)g,
      (__attribute__((address_space(3))) void*)l, 16, 0, 0);
}

// ---------------------------------------------------------------------------
// gemm_lt: 128x256 tile, 2-phase, single-buffered 48KB LDS, ~110 regs -> 2
// blocks/CU. Short-K GEMMs with LARGE grids (>=512 blocks).
// MODE 0: bf16 out, bias = col-select (bias_col col<512, bias_col2 col>=512)
// MODE 1: bf16 out, C = exp2(alpha*acc)
// ---------------------------------------------------------------------------
template <int MODE>
__global__ __launch_bounds__(512, 4) void gemm_lt(
    const u16* __restrict__ A, int lda, unsigned long long sA,
    const u16* __restrict__ Bt, int ldb, unsigned long long sB,
    u16* __restrict__ Cout, int ldc, unsigned long long sC,
    int K, float alpha, int tn,
    const float* __restrict__ bias_col, const float* __restrict__ bias_col2) {
  __shared__ u16 lds[24576];   // As[128][64] @0, Bs[256][64] @8192 (48KB)
  u16* As = lds;
  u16* Bs = lds + 8192;

  const int t = threadIdx.x;
  const int lane = t & 63;
  const int w = t >> 6;
  const int bz = blockIdx.z;
  A  += (size_t)bz * sA;
  Bt += (size_t)bz * sB;

  // XCD swizzle (nwg % 8 == 0 guaranteed by launch)
  const int nwg = gridDim.x;
  const int flat = blockIdx.x;
  const int wg = (flat & 7) * (nwg >> 3) + (flat >> 3);
  const int m0 = (wg / tn) * 128;
  const int n0 = (wg % tn) * 256;

  const int NKT = K >> 6;

  // staging source per lane: row = +sr, col16 = (lane&7) ^ sr  (pre-swizzle)
  const int sr = lane >> 3;
  const int sc = ((lane & 7) ^ sr) * 8;
  const u16* gA = A  + (size_t)(m0 + w * 16 + sr) * lda + sc;   // 2 loads/wave
  const u16* gB = Bt + (size_t)(n0 + w * 32 + sr) * ldb + sc;   // 4 loads/wave
  const size_t a8 = (size_t)8 * lda, b8 = (size_t)8 * ldb;
  u16* lA = As + w * 1024;
  u16* lB = Bs + w * 2048;

  const int wr = w >> 2, wc = w & 3;     // 2 (M) x 4 (N) waves
  const int fr = lane & 15, kg = lane >> 4;
  const int frx = (fr & 7) << 4;

  f32x4 acc[4][4] = {};                  // 64 regs
  bf16x8 af[4][2];                       // 32 regs
  bf16x8 bqn[2];                         // 8 regs

  for (int kt = 0; kt < NKT; ++kt) {
    if (kt) __builtin_amdgcn_s_barrier();         // prev tile fully consumed
    {
      const size_t ko = (size_t)kt * 64;
      gl_lds16(gA + ko, lA);
      gl_lds16(gA + a8 + ko, lA + 512);
#pragma unroll
      for (int j = 0; j < 4; ++j)
        gl_lds16(gB + (size_t)j * b8 + ko, lB + j * 512);
    }
    asm volatile("s_waitcnt vmcnt(0)" ::: "memory");
    __builtin_amdgcn_s_barrier();                 // tile resident

#pragma unroll
    for (int m = 0; m < 4; ++m) {
      const int R = wr * 64 + m * 16 + fr;
#pragma unroll
      for (int kk = 0; kk < 2; ++kk)
        af[m][kk] = *reinterpret_cast<const bf16x8*>(
            As + R * 64 + (((kk * 64 + kg * 16) ^ frx) >> 1));
    }
#pragma unroll
    for (int n = 0; n < 4; ++n) {
      const int R = wc * 64 + n * 16 + fr;
#pragma unroll
      for (int kk = 0; kk < 2; ++kk)
        bqn[kk] = *reinterpret_cast<const bf16x8*>(
            Bs + R * 64 + (((kk * 64 + kg * 16) ^ frx) >> 1));
#pragma unroll
      for (int kk = 0; kk < 2; ++kk)
#pragma unroll
        for (int m = 0; m < 4; ++m)
          acc[m][n] = __builtin_amdgcn_mfma_f32_16x16x32_bf16(
              af[m][kk], bqn[kk], acc[m][n], 0, 0, 0);
    }
  }

  // epilogue: two 64x256 halves (32KB) through LDS, coalesced stores
  u16* cs = lds;
  const size_t cbs = (size_t)bz * sC;
#pragma unroll
  for (int h = 0; h < 2; ++h) {
    __syncthreads();
    if (wr == h) {
#pragma unroll
      for (int m = 0; m < 4; ++m) {
        const int rl = m * 16 + (kg << 2);
#pragma unroll
        for (int n = 0; n < 4; ++n) {
          const int col = wc * 64 + n * 16 + fr;
          float bcc = 0.0f;
          if (MODE == 0 && bias_col) {
            const int gc = n0 + col;
            bcc = (bias_col2 && gc >= 512) ? bias_col2[gc - 512] : bias_col[gc & 511];
          }
#pragma unroll
          for (int r = 0; r < 4; ++r) {
            float v = acc[m][n][r] * alpha;
            if (MODE == 1) v = exp2f(v);
            else v += bcc;
            cs[(rl + r) * 256 + col] = f2bf(v);
          }
        }
      }
    }
    __syncthreads();
#pragma unroll
    for (int it = 0; it < 4; ++it) {
      const int off = (it * 512 + t) * 8;
      const int row = off >> 8, col = off & 255;
      *reinterpret_cast<uint4*>(
          &Cout[cbs + (size_t)(m0 + h * 64 + row) * ldc + (n0 + col)]) =
          *reinterpret_cast<const uint4*>(&cs[off]);
    }
  }
}

// ---------------------------------------------------------------------------
// 256x256 8-phase GEMM (PV): MODE 2 = C=acc + row-sums of A via ones-MFMA.
// blockIdx.y = K-split index: K elems [y*K,(y+1)*K), out += y*sSplit.
// ---------------------------------------------------------------------------
template <int MODE>
__global__ __launch_bounds__(512, 2) void gemm_nt256(
    const u16* __restrict__ A, int lda, unsigned long long sA,
    const u16* __restrict__ Bt, int ldb, unsigned long long sB,
    u16* __restrict__ Cout, int ldc, unsigned long long sC,
    unsigned long long sSplit, int K, float alpha, int tn,
    float* __restrict__ psum) {
  __shared__ u16 lds[2][4][8192];

  const int t = threadIdx.x;
  const int lane = t & 63;
  const int w = t >> 6;
  const int bz = blockIdx.z;
  A  += (size_t)bz * sA + (size_t)blockIdx.y * K;
  Bt += (size_t)bz * sB + (size_t)blockIdx.y * K;
  Cout += (size_t)blockIdx.y * sSplit;

  const int nwg = gridDim.x;
  const int flat = blockIdx.x;
  const int wg = (flat & 7) * (nwg >> 3) + (flat >> 3);
  const int tt = tn << 1;
  const int p  = wg / tt;
  const int rr = wg - p * tt;
  const int m0 = (p * 2 + (rr & 1)) * 256;
  const int n0 = (rr >> 1) * 256;

  const int NKT = K >> 6;

  const int sr = lane >> 3;
  const int sc = ((lane & 7) ^ sr) * 8;
  const u16* gA = A  + (size_t)(m0 + w * 16 + sr) * lda + sc;
  const u16* gB = Bt + (size_t)(n0 + w * 16 + sr) * ldb + sc;
  const size_t a128 = (size_t)128 * lda, b128 = (size_t)128 * ldb;
  const size_t a8 = (size_t)8 * lda, b8 = (size_t)8 * ldb;
  const int lws = w * 1024;

  auto stage = [&](int slot, int region, int kt) {
    kt = kt < NKT ? kt : NKT - 1;
    u16* l = &lds[slot][region][lws];
    if (region < 2) {
      const u16* g = gA + (region ? a128 : 0) + (size_t)kt * 64;
      gl_lds16(g, l);
      gl_lds16(g + a8, l + 512);
    } else {
      const u16* g = gB + (region == 3 ? b128 : 0) + (size_t)kt * 64;
      gl_lds16(g, l);
      gl_lds16(g + b8, l + 512);
    }
  };

  const int wr = w >> 2, wc = w & 3;
  const int fr = lane & 15, kg = lane >> 4;
  const int frx = (fr & 7) << 4;

  f32x4 acc[8][4] = {};
  f32x4 sacc[8] = {};
  bf16x8 af[4][2], bq[2][2];
  union { u16 u[8]; bf16x8 v; } ou;
#pragma unroll
  for (int i = 0; i < 8; ++i) ou.u[i] = 0x3F80;   // bf16 1.0
  const bf16x8 onesb = ou.v;

#define LDA_(s, qm)                                                            \
  {                                                                            \
    const u16* Ab = &lds[s][0][0];                                             \
    _Pragma("unroll") for (int m = 0; m < 4; ++m) {                            \
      const int R = wr * 128 + (qm) * 64 + m * 16 + fr;                        \
      _Pragma("unroll") for (int kk = 0; kk < 2; ++kk)                         \
          af[m][kk] = *reinterpret_cast<const bf16x8*>(                        \
              Ab + R * 64 + (((kk * 64 + kg * 16) ^ frx) >> 1));               \
    }                                                                          \
  }
#define LDB_(s, qn)                                                            \
  {                                                                            \
    const u16* Bb = &lds[s][2][0];                                             \
    _Pragma("unroll") for (int n = 0; n < 2; ++n) {                            \
      const int R = wc * 64 + (qn) * 32 + n * 16 + fr;                         \
      _Pragma("unroll") for (int kk = 0; kk < 2; ++kk)                         \
          bq[n][kk] = *reinterpret_cast<const bf16x8*>(                        \
              Bb + R * 64 + (((kk * 64 + kg * 16) ^ frx) >> 1));               \
    }                                                                          \
  }
#define PH(s, qm, qn, DOA, DOB, ss, rr_, kt, VM)                               \
  {                                                                            \
    if (DOA) LDA_(s, qm)                                                       \
    if (DOB) LDB_(s, qn)                                                       \
    stage(ss, rr_, kt);                                                        \
    __builtin_amdgcn_s_barrier();                                              \
    asm volatile("s_waitcnt lgkmcnt(0)" ::: "memory");                         \
    __builtin_amdgcn_s_setprio(1);                                             \
    _Pragma("unroll") for (int kk = 0; kk < 2; ++kk)                           \
    _Pragma("unroll") for (int m = 0; m < 4; ++m)                              \
    _Pragma("unroll") for (int n = 0; n < 2; ++n)                              \
        acc[(qm)*4 + m][(qn)*2 + n] = __builtin_amdgcn_mfma_f32_16x16x32_bf16( \
            af[m][kk], bq[n][kk], acc[(qm)*4 + m][(qn)*2 + n], 0, 0, 0);       \
    if (MODE == 2 && (DOA) && wc == 0) {                                       \
      _Pragma("unroll") for (int kk = 0; kk < 2; ++kk)                         \
      _Pragma("unroll") for (int m = 0; m < 4; ++m)                            \
          sacc[(qm)*4 + m] = __builtin_amdgcn_mfma_f32_16x16x32_bf16(          \
              af[m][kk], onesb, sacc[(qm)*4 + m], 0, 0, 0);                    \
    }                                                                          \
    __builtin_amdgcn_s_setprio(0);                                             \
    if (VM) asm volatile("s_waitcnt vmcnt(2)" ::: "memory");                   \
    __builtin_amdgcn_s_barrier();                                              \
  }

  stage(0, 0, 0); stage(0, 1, 0); stage(0, 2, 0); stage(0, 3, 0);
  stage(1, 0, 1);
  asm volatile("s_waitcnt vmcnt(2)" ::: "memory");
  __builtin_amdgcn_s_barrier();

  for (int j = 0; j < (NKT >> 1); ++j) {
    const int k1 = 2 * j + 1, k2 = 2 * j + 2, k3 = 2 * j + 3;
    PH(0, 0, 0, 1, 1, 1, 1, k1, 0)
    PH(0, 0, 1, 0, 1, 1, 2, k1, 0)
    PH(0, 1, 1, 1, 0, 1, 3, k1, 0)
    PH(0, 1, 0, 0, 1, 0, 0, k2, 1)
    PH(1, 0, 0, 1, 1, 0, 1, k2, 0)
    PH(1, 0, 1, 0, 1, 0, 2, k2, 0)
    PH(1, 1, 1, 1, 0, 0, 3, k2, 0)
    PH(1, 1, 0, 0, 1, 1, 0, k3, 1)
  }
#undef PH
#undef LDB_
#undef LDA_

  __syncthreads();
  u16* cs = &lds[0][0][0];
#pragma unroll
  for (int a = 0; a < 8; ++a) {
    const int row = wr * 128 + a * 16 + (kg << 2);
#pragma unroll
    for (int b = 0; b < 4; ++b) {
      const int col = wc * 64 + b * 16 + fr;
#pragma unroll
      for (int r = 0; r < 4; ++r)
        cs[(row + r) * 256 + col] = f2bf(acc[a][b][r] * alpha);
    }
  }
  __syncthreads();
  const size_t cbs = (size_t)bz * sC;
#pragma unroll
  for (int it = 0; it < 16; ++it) {
    const int off = (it * 512 + t) * 8;
    const int row = off >> 8, col = off & 255;
    *reinterpret_cast<uint4*>(&Cout[cbs + (size_t)(m0 + row) * ldc + (n0 + col)]) =
        *reinterpret_cast<const uint4*>(&cs[off]);
  }
  if (MODE == 2 && psum && wc == 0 && fr == 0) {
    const int Mrows = (nwg / tn) << 8;
    float* pp = psum + ((size_t)bz * gridDim.y + blockIdx.y) * Mrows + m0;
#pragma unroll
    for (int q = 0; q < 2; ++q)
#pragma unroll
      for (int m = 0; m < 4; ++m)
#pragma unroll
        for (int r = 0; r < 4; ++r)
          pp[wr * 128 + q * 64 + m * 16 + (kg << 2) + r] = sacc[q * 4 + m][r];
  }
}

// ---------------------------------------------------------------------------
// 128x128 m97-structure GEMM (v projection; generic fallback proj)
// ---------------------------------------------------------------------------
template <bool OUT_F32>
__global__ __launch_bounds__(256) void gemm_nt(
    const u16* __restrict__ A, int lda, unsigned long long sA,
    const u16* __restrict__ Bt, int ldb, unsigned long long sB,
    void* __restrict__ Cout, int ldc, unsigned long long sC,
    int K, float alpha,
    const float* __restrict__ bias_row, const float* __restrict__ bias_col,
    const float* __restrict__ residual, unsigned long long sRes) {
  __shared__ u16 lds[128 * 128];
  u16* As = lds;
  u16* Bs = lds + 8192;

  const int t = threadIdx.x;
  const int bz = blockIdx.z;
  A  += (size_t)bz * sA;
  Bt += (size_t)bz * sB;
  const int m0 = blockIdx.x * 128;
  const int n0 = blockIdx.y * 128;

  const int lane = t & 63;
  const int w = t >> 6;

  const int srow = w * 32 + (lane >> 3);
  const int scol = (lane & 7) * 8;
  const u16* gA = A  + (size_t)(m0 + srow) * lda + scol;
  const u16* gB = Bt + (size_t)(n0 + srow) * ldb + scol;
  u16* lA = As + w * 2048;
  u16* lB = Bs + w * 2048;

  f32x4 acc[4][4] = {};
  const int wm = (w >> 1) * 64;
  const int wn = (w & 1) * 64;
  const int fr = lane & 15;
  const int kg = lane >> 4;

  for (int k0 = 0; k0 < K; k0 += 64) {
    __syncthreads();
#pragma unroll
    for (int i = 0; i < 4; ++i) {
      gl_lds16(gA + (size_t)(i * 8) * lda + k0, lA + i * 512);
      gl_lds16(gB + (size_t)(i * 8) * ldb + k0, lB + i * 512);
    }
    __syncthreads();

#pragma unroll
    for (int kk = 0; kk < 2; ++kk) {
      bf16x8 af[4], bfr[4];
#pragma unroll
      for (int m = 0; m < 4; ++m)
        af[m] = *reinterpret_cast<const bf16x8*>(
            &As[(wm + m * 16 + fr) * 64 + kk * 32 + kg * 8]);
#pragma unroll
      for (int n = 0; n < 4; ++n)
        bfr[n] = *reinterpret_cast<const bf16x8*>(
            &Bs[(wn + n * 16 + fr) * 64 + kk * 32 + kg * 8]);
#pragma unroll
      for (int m = 0; m < 4; ++m)
#pragma unroll
        for (int n = 0; n < 4; ++n)
          acc[m][n] = __builtin_amdgcn_mfma_f32_16x16x32_bf16(af[m], bfr[n], acc[m][n], 0, 0, 0);
    }
  }

  const size_t cbase = (size_t)bz * sC;
  const size_t rbase = (size_t)bz * sRes;
  const int rq = kg * 4;

  if (OUT_F32) {
    float* Cf = reinterpret_cast<float*>(Cout);
    float* lf = reinterpret_cast<float*>(lds);
#pragma unroll
    for (int h = 0; h < 2; ++h) {
      __syncthreads();
      if ((wm >> 6) == h) {
#pragma unroll
        for (int m = 0; m < 4; ++m)
#pragma unroll
          for (int n = 0; n < 4; ++n) {
            const float bc = bias_col ? bias_col[n0 + wn + n * 16 + fr] : 0.0f;
#pragma unroll
            for (int r = 0; r < 4; ++r)
              lf[(m * 16 + rq + r) * 128 + (wn + n * 16 + fr)] =
                  acc[m][n][r] * alpha + bc;
          }
      }
      __syncthreads();
#pragma unroll
      for (int it = 0; it < 8; ++it) {
        const int off = (it * 256 + t) * 4;
        const int row = off >> 7, col = off & 127;
        const int grow = m0 + h * 64 + row, gcol = n0 + col;
        float4 v = *reinterpret_cast<const float4*>(&lf[off]);
        if (bias_row) {
          const float br = bias_row[grow];
          v.x += br; v.y += br; v.z += br; v.w += br;
        }
        if (residual) {
          const float4 rx = *reinterpret_cast<const float4*>(
              &residual[rbase + (size_t)grow * ldc + gcol]);
          v.x += rx.x; v.y += rx.y; v.z += rx.z; v.w += rx.w;
        }
        *reinterpret_cast<float4*>(&Cf[cbase + (size_t)grow * ldc + gcol]) = v;
      }
    }
  } else {
    __syncthreads();
#pragma unroll
    for (int m = 0; m < 4; ++m) {
#pragma unroll
      for (int n = 0; n < 4; ++n) {
        const int gcol = n0 + wn + n * 16 + fr;
        const float bc = bias_col ? bias_col[gcol] : 0.0f;
#pragma unroll
        for (int r = 0; r < 4; ++r) {
          const int grow = m0 + wm + m * 16 + rq + r;
          float v = acc[m][n][r] * alpha + bc;
          if (bias_row) v += bias_row[grow];
          lds[(wm + m * 16 + rq + r) * 128 + (wn + n * 16 + fr)] = f2bf(v);
        }
      }
    }
    __syncthreads();
    u16* Cb = reinterpret_cast<u16*>(Cout);
#pragma unroll
    for (int j = 0; j < 8; ++j) {
      const int off = (j * 256 + t) * 8;
      const int row = off >> 7, col = off & 127;
      *reinterpret_cast<uint4*>(&Cb[cbase + (size_t)(m0 + row) * ldc + (n0 + col)]) =
          *reinterpret_cast<const uint4*>(&lds[off]);
    }
  }
}

// ---------------------------------------------------------------------------
// Final projection with fused split-K combine + softmax normalize:
//   out[bz][co][n] = wo[co][:] . ((p0[bz][n][:] + p1[bz][n][:]) * il[n]) + bo[co] + x[bz][co][n]
// Identical structure to gemm_nt<true>; only the B-side staging is reg-staged
// (load 2 bf16 partials, add, scale by il[row], pack, ds_write to the same
// linear LDS slot gl_lds16 would fill). Arithmetic bit-identical to
// reduce_pv -> gemm_nt<true>.
// ---------------------------------------------------------------------------
__global__ __launch_bounds__(256) void gemm_proj_norm(
    const u16* __restrict__ A, int lda,                 // wo_b [512][512]
    const u16* __restrict__ P0, unsigned long long sHalf,  // o_part; split stride
    const float* __restrict__ psum, int Nn,             // [bz*2+s][Nn]
    float* __restrict__ Cout, int ldc, unsigned long long sC,
    int K, const float* __restrict__ bias_row,
    const float* __restrict__ residual, unsigned long long sRes) {
  __shared__ u16 lds[128 * 128];
  u16* As = lds;
  u16* Bs = lds + 8192;

  const int t = threadIdx.x;
  const int bz = blockIdx.z;
  const int m0 = blockIdx.x * 128;     // co
  const int n0 = blockIdx.y * 128;     // n

  const int lane = t & 63;
  const int w = t >> 6;

  const int srow = w * 32 + (lane >> 3);
  const int scol = (lane & 7) * 8;
  const u16* gA = A + (size_t)(m0 + srow) * lda + scol;
  u16* lA = As + w * 2048;
  u16* lB = Bs + w * 2048;

  // per-lane rows for B staging are kt-invariant -> hoist il[4]
  const float* ps0 = psum + (size_t)(bz * 2) * Nn;
  const float* ps1 = psum + (size_t)(bz * 2 + 1) * Nn;
  float il[4];
#pragma unroll
  for (int i = 0; i < 4; ++i) {
    const int row = n0 + srow + i * 8;
    il[i] = 1.0f / (ps0[row] + ps1[row]);
  }
  const u16* gP = P0 + ((size_t)bz * Nn + (size_t)(n0 + srow)) * 512 + scol;

  f32x4 acc[4][4] = {};
  const int wm = (w >> 1) * 64;
  const int wn = (w & 1) * 64;
  const int fr = lane & 15;
  const int kg = lane >> 4;

  for (int k0 = 0; k0 < K; k0 += 64) {
    __syncthreads();                  // prev tile consumed
#pragma unroll
    for (int i = 0; i < 4; ++i)
      gl_lds16(gA + (size_t)(i * 8) * lda + k0, lA + i * 512);
#pragma unroll
    for (int i = 0; i < 4; ++i) {     // B: combine+normalize in registers
      const u16* bp = gP + (size_t)(i * 8) * 512 + k0;
      uint4 ua = *reinterpret_cast<const uint4*>(bp);
      uint4 ub = *reinterpret_cast<const uint4*>(bp + sHalf);
      float fa[8], fb[8];
      unp8(ua, fa); unp8(ub, fb);
#pragma unroll
      for (int j = 0; j < 8; ++j) fa[j] = (fa[j] + fb[j]) * il[i];
      *reinterpret_cast<uint4*>(&lB[i * 512 + lane * 8]) = pk8(fa);
    }
    __syncthreads();                  // drains vmcnt (DMA) + lgkmcnt (ds_write)

#pragma unroll
    for (int kk = 0; kk < 2; ++kk) {
      bf16x8 af[4], bfr[4];
#pragma unroll
      for (int m = 0; m < 4; ++m)
        af[m] = *reinterpret_cast<const bf16x8*>(
            &As[(wm + m * 16 + fr) * 64 + kk * 32 + kg * 8]);
#pragma unroll
      for (int n = 0; n < 4; ++n)
        bfr[n] = *reinterpret_cast<const bf16x8*>(
            &Bs[(wn + n * 16 + fr) * 64 + kk * 32 + kg * 8]);
#pragma unroll
      for (int m = 0; m < 4; ++m)
#pragma unroll
        for (int n = 0; n < 4; ++n)
          acc[m][n] = __builtin_amdgcn_mfma_f32_16x16x32_bf16(af[m], bfr[n], acc[m][n], 0, 0, 0);
    }
  }

  const size_t cbase = (size_t)bz * sC;
  const size_t rbase = (size_t)bz * sRes;
  const int rq = kg * 4;

  float* lf = reinterpret_cast<float*>(lds);
#pragma unroll
  for (int h = 0; h < 2; ++h) {
    __syncthreads();
    if ((wm >> 6) == h) {
#pragma unroll
      for (int m = 0; m < 4; ++m)
#pragma unroll
        for (int n = 0; n < 4; ++n)
#pragma unroll
          for (int r = 0; r < 4; ++r)
            lf[(m * 16 + rq + r) * 128 + (wn + n * 16 + fr)] = acc[m][n][r];
    }
    __syncthreads();
#pragma unroll
    for (int it = 0; it < 8; ++it) {
      const int off = (it * 256 + t) * 4;
      const int row = off >> 7, col = off & 127;
      const int grow = m0 + h * 64 + row, gcol = n0 + col;
      float4 v = *reinterpret_cast<const float4*>(&lf[off]);
      const float br = bias_row ? bias_row[grow] : 0.0f;
      const float4 rx = *reinterpret_cast<const float4*>(
          &residual[rbase + (size_t)grow * ldc + gcol]);
      v.x += br + rx.x; v.y += br + rx.y; v.z += br + rx.z; v.w += br + rx.w;
      *reinterpret_cast<float4*>(&Cout[cbase + (size_t)grow * ldc + gcol]) = v;
    }
  }
}

// ---------------------------------------------------------------------------
// GroupNorm, split for full-GPU occupancy: gn_part (partial sums per N/4
// chunk, 512 blocks) + gn_apply (normalize+write, 512 blocks).
// x fp32 [B,C,N] -> h_t bf16 [B,N,C]; group = 16 channels.
// ---------------------------------------------------------------------------
__global__ __launch_bounds__(256) void gn_part(
    const float* __restrict__ x, float2* __restrict__ part, int C, int N) {
  const int g = blockIdx.x, b = blockIdx.y, ch = blockIdx.z;
  const int t = threadIdx.x;
  const float* xb = x + ((size_t)b * C + g * 16) * N + ch * (N >> 2);

  float s = 0.f, q = 0.f;
#pragma unroll
  for (int c = 0; c < 16; ++c) {
    const float4 v = reinterpret_cast<const float4*>(xb + (size_t)c * N)[t];
    s += v.x + v.y + v.z + v.w;
    q += v.x * v.x + v.y * v.y + v.z * v.z + v.w * v.w;
  }
#pragma unroll
  for (int o = 32; o > 0; o >>= 1) { s += __shfl_down(s, o); q += __shfl_down(q, o); }
  __shared__ float rs[4], rq[4];
  const int lane = t & 63, wid = t >> 6;
  if (lane == 0) { rs[wid] = s; rq[wid] = q; }
  __syncthreads();
  if (t == 0) {
    part[(((size_t)b * 32 + g) << 2) + ch] =
        make_float2(rs[0] + rs[1] + rs[2] + rs[3], rq[0] + rq[1] + rq[2] + rq[3]);
  }
}

__global__ __launch_bounds__(256) void gn_apply(
    const float* __restrict__ x, const float* __restrict__ gamma,
    const float* __restrict__ beta, const float2* __restrict__ part,
    u16* __restrict__ h_t, int C, int N) {
  const int g = blockIdx.x, b = blockIdx.y, ch = blockIdx.z;
  const int t = threadIdx.x;
  const float2* pp = &part[(((size_t)b * 32 + g) << 2)];
  const float2 p0 = pp[0], p1 = pp[1], p2 = pp[2], p3 = pp[3];
  const float S = p0.x + p1.x + p2.x + p3.x;
  const float Q = p0.y + p1.y + p2.y + p3.y;
  const float inv = 1.0f / (16.0f * (float)N);
  const float mean = S * inv;
  const float rstd = rsqrtf(Q * inv - mean * mean + 1e-6f);

  float gm[16], bt[16];
#pragma unroll
  for (int c = 0; c < 16; ++c) {
    gm[c] = gamma[g * 16 + c] * rstd;
    bt[c] = beta[g * 16 + c] - mean * gm[c];
  }
  const float* xb = x + ((size_t)b * C + g * 16) * N;
  u16* ho = h_t + (size_t)b * N * C + g * 16;
  const int n0 = ch * (N >> 2);
  for (int n = n0 + t; n < n0 + (N >> 2); n += 256) {
    union { u16 us[16]; uint4 v4[2]; } pk;
#pragma unroll
    for (int c = 0; c < 16; ++c) {
      float v = xb[(size_t)c * N + n];
      pk.us[c] = f2bf(v * gm[c] + bt[c]);
    }
    uint4* dst = reinterpret_cast<uint4*>(ho + (size_t)n * C);
    dst[0] = pk.v4[0];
    dst[1] = pk.v4[1];
  }
}

// convert 4 fp32 weight matrices (each n elems) to bf16, contiguous dst
__global__ __launch_bounds__(256) void wcvt4(
    const float* __restrict__ s0, const float* __restrict__ s1,
    const float* __restrict__ s2, const float* __restrict__ s3,
    u16* __restrict__ dst, int n) {
  const int i = (blockIdx.x * 256 + threadIdx.x) * 8;
  if (i >= n) return;
  const float* src = (blockIdx.y == 0) ? s0 : (blockIdx.y == 1) ? s1
                     : (blockIdx.y == 2) ? s2 : s3;
  const float4* s4 = reinterpret_cast<const float4*>(src + i);
  float4 a = s4[0], b = s4[1];
  float f[8] = {a.x, a.y, a.z, a.w, b.x, b.y, b.z, b.w};
  *reinterpret_cast<uint4*>(dst + (size_t)blockIdx.y * n + i) = pk8(f);
}

// in-place o[i] /= psum[row]   (fallback path, unsplit PV, psum [b*N+n])
__global__ __launch_bounds__(256) void scale_o(u16* __restrict__ o,
                                               const float* __restrict__ psum,
                                               int n) {
  const int i = (blockIdx.x * 256 + threadIdx.x) * 8;
  if (i >= n) return;
  const float il = 1.0f / psum[i >> 9];
  uint4 a = *reinterpret_cast<const uint4*>(o + i);
  float fa[8];
  unp8(a, fa);
#pragma unroll
  for (int j = 0; j < 8; ++j) fa[j] *= il;
  *reinterpret_cast<uint4*>(o + i) = pk8(fa);
}

extern "C" void kernel_launch(void* const* d_in, const int* in_sizes, int n_in,
                              void* d_out, int out_size, void* d_ws, size_t ws_size,
                              hipStream_t stream) {
  const float* x     = (const float*)d_in[0];
  const float* gamma = (const float*)d_in[1];
  const float* beta  = (const float*)d_in[2];
  const float* wq    = (const float*)d_in[3];
  const float* bq    = (const float*)d_in[4];
  const float* wk    = (const float*)d_in[5];
  const float* bk    = (const float*)d_in[6];
  const float* wv    = (const float*)d_in[7];
  const float* bv    = (const float*)d_in[8];
  const float* wo    = (const float*)d_in[9];
  const float* bo    = (const float*)d_in[10];

  const int B = 4, C = 512, N = 4096;
  const size_t NC = (size_t)N * C;
  const size_t NN = (size_t)N * N;
  const size_t CC = (size_t)C * C;

  char* ws = (char*)d_ws;
  size_t off = 0;
  auto alloc = [&](size_t bytes) {
    size_t r = off;
    off = (off + bytes + 255) & ~(size_t)255;
    return r;
  };
  u16* wq_b = (u16*)(ws + alloc(CC * 2));   // wq,wk,wv,wo contiguous bf16
  u16* wk_b = (u16*)(ws + alloc(CC * 2));
  u16* wv_b = (u16*)(ws + alloc(CC * 2));
  u16* wo_b = (u16*)(ws + alloc(CC * 2));
  u16* h_t  = (u16*)(ws + alloc(B * NC * 2));
  u16* qk_t = (u16*)(ws + alloc(B * N * 1024 * 2));  // q|k; reused as PV partials
  u16* v_cn = (u16*)(ws + alloc(B * NC * 2));
  u16* o_t  = (u16*)(ws + alloc(B * NC * 2));
  float* psum = (float*)(ws + alloc((size_t)B * 2 * N * 4));  // row-sum partials
  float2* gnp = (float2*)(ws + alloc((size_t)B * 32 * 4 * 8));
  const size_t base_need = off;

  int s_batched = 0;
  u16* S;
  if (ws_size >= base_need + B * NN * 2) {
    S = (u16*)(ws + alloc(B * NN * 2));
    s_batched = 1;
  } else {
    S = (u16*)(ws + alloc(NN * 2));   // per-batch scores (assumed to fit)
  }
  u16* o_part = qk_t;   // 2 x B*NC bf16 == B*N*1024 bf16; qk_t dead after QK

  (void)wk_b;

  // weights fp32 -> bf16 (one launch, 4 matrices)
  wcvt4<<<dim3(CC / 2048, 4), 256, 0, stream>>>(wq, wk, wv, wo, wq_b, (int)CC);

  // groupnorm, split for full-GPU occupancy -> h_t [b,n,c]
  gn_part<<<dim3(32, B, 4), 256, 0, stream>>>(x, gnp, C, N);
  gn_apply<<<dim3(32, B, 4), 256, 0, stream>>>(x, gamma, beta, gnp, h_t, C, N);

  // fused q|k : qk_t[b,n,0:512]=q, [512:1024]=k  (128x256 lt kernel, 2/CU)
  gemm_lt<0><<<dim3((N / 128) * (1024 / 256), 1, B), 512, 0, stream>>>(
      h_t, C, NC, wq_b, C, 0, qk_t, 1024, (unsigned long long)N * 1024,
      C, 1.0f, 1024 / 256, bq, bk);
  // v : [b,co,n] = w[co,ci] * h_t[b,n,ci]^T + bv[co]  (512-block 128^2 kernel)
  dim3 gv(C / 128, N / 128, B);
  gemm_nt<false><<<gv, 256, 0, stream>>>(wv_b, C, 0, h_t, C, NC, v_cn, N, NC,
                                         C, 1.0f, bv, nullptr, nullptr, 0);

  // alpha folds 512^-0.5 and log2(e): S' = 2^(qk * alpha) = e^(qk * 512^-0.5)
  const float c1 = 0.06376694387439652f;
  if (s_batched) {
    // QK -> unnormalized P (bf16), 128x256 lt kernel (2 blocks/CU)
    gemm_lt<1><<<dim3((N / 128) * (N / 256), 1, B), 512, 0, stream>>>(
        qk_t, 1024, (unsigned long long)N * 1024, qk_t + 512, 1024,
        (unsigned long long)N * 1024, S, N, NN, C, c1, N / 256,
        nullptr, nullptr);
    // PV split-K=2: partials (alias qk_t) + exact row-sums via ones-MFMA
    gemm_nt256<2><<<dim3((N / 256) * (C / 256), 2, B), 512, 0, stream>>>(
        S, N, NN, v_cn, N, NC, o_part, C, NC, (unsigned long long)B * NC,
        N / 2, 1.0f, C / 256, psum);
    // final proj with fused combine+normalize (replaces reduce_pv + gemm_nt<true>)
    gemm_proj_norm<<<dim3(C / 128, N / 128, B), 256, 0, stream>>>(
        wo_b, C, o_part, (unsigned long long)B * NC, psum, N,
        (float*)d_out, N, NC, C, bo, x, NC);
  } else {
    for (int b = 0; b < B; ++b) {
      gemm_lt<1><<<dim3((N / 128) * (N / 256), 1, 1), 512, 0, stream>>>(
          qk_t + (size_t)b * N * 1024, 1024, 0, qk_t + (size_t)b * N * 1024 + 512,
          1024, 0, S, N, 0, C, c1, N / 256, nullptr, nullptr);
      gemm_nt256<2><<<dim3((N / 256) * (C / 256), 1, 1), 512, 0, stream>>>(
          S, N, 0, v_cn + (size_t)b * NC, N, 0, o_t + (size_t)b * NC, C, 0, 0,
          N, 1.0f, C / 256, psum + (size_t)b * N);
    }
    scale_o<<<dim3((int)(B * NC / 2048)), 256, 0, stream>>>(o_t, psum, (int)(B * NC));
    dim3 gf(C / 128, N / 128, B);
    gemm_nt<true><<<gf, 256, 0, stream>>>(wo_b, C, 0, o_t, C, NC, d_out, N, NC,
                                          C, 1.0f, bo, nullptr, x, NC);
  }
}